// Round 1
// baseline (200.106 us; speedup 1.0000x reference)
//
#include <hip/hip_runtime.h>

// ---------------- problem constants ----------------
#define DIM     384
#define QKV_CH  1152          // 3*DIM
#define HD      32            // head dim
#define CD      128           // channels per dilation group (4 heads)
#define BATCH   4
#define SEQ     8192
#define ROWS    (BATCH*SEQ)   // 32768
#define SCALE   0.17677669529663687f   // 32^-0.5

typedef short bf16x8 __attribute__((ext_vector_type(8)));
typedef float f32x4  __attribute__((ext_vector_type(4)));

__device__ __forceinline__ unsigned short f2bf(float f) {
  unsigned int u = __float_as_uint(f);
  u += 0x7fffu + ((u >> 16) & 1u);      // RNE
  return (unsigned short)(u >> 16);
}
__device__ __forceinline__ float bf2f(unsigned short b) {
  return __uint_as_float(((unsigned int)b) << 16);
}
__device__ __forceinline__ void unpack8(uint4 u, float* f) {
  f[0] = bf2f((unsigned short)(u.x & 0xffffu)); f[1] = bf2f((unsigned short)(u.x >> 16));
  f[2] = bf2f((unsigned short)(u.y & 0xffffu)); f[3] = bf2f((unsigned short)(u.y >> 16));
  f[4] = bf2f((unsigned short)(u.z & 0xffffu)); f[5] = bf2f((unsigned short)(u.z >> 16));
  f[6] = bf2f((unsigned short)(u.w & 0xffffu)); f[7] = bf2f((unsigned short)(u.w >> 16));
}

// ---------------- fp32 -> bf16 convert ----------------
__global__ __launch_bounds__(256) void cvt_f32_bf16(const float* __restrict__ in,
                                                    unsigned short* __restrict__ out,
                                                    int n4) {
  int i = blockIdx.x * 256 + threadIdx.x;
  if (i >= n4) return;
  float4 v = ((const float4*)in)[i];
  ushort4 o;
  o.x = f2bf(v.x); o.y = f2bf(v.y); o.z = f2bf(v.z); o.w = f2bf(v.w);
  ((ushort4*)out)[i] = o;
}

// ---------------- bf16 MFMA GEMM:  C[M,Nt] = A[M,K] * Bt[Nt,K]^T + bias ----------------
// 128x128 tile, BK=32, 256 threads = 4 waves, each wave a 64x64 quadrant (4x4 MFMA tiles).
// Requires M%128==0, Nt%128==0, K%32==0 (holds: 32768, 1152/384, 384).
template<int OUT_BF16>
__global__ __launch_bounds__(256) void gemm_bt(const unsigned short* __restrict__ A,
                                               const unsigned short* __restrict__ Bt,
                                               const float* __restrict__ bias,
                                               void* __restrict__ Cv,
                                               int M, int Nt, int K) {
  __shared__ unsigned short As[128 * 32];
  __shared__ unsigned short Bs[128 * 32];
  const int t = threadIdx.x;
  const int wave = t >> 6, lane = t & 63;
  const int quad = lane >> 4, l16 = lane & 15;
  const int row0 = blockIdx.x * 128, col0 = blockIdx.y * 128;
  const int wm = (wave & 1) * 64, wn = (wave >> 1) * 64;

  f32x4 acc[4][4] = {};

  for (int k0 = 0; k0 < K; k0 += 32) {
    // stage A,B tiles: 512 chunks of 16B each per tile, 2 per thread per tile
#pragma unroll
    for (int r = 0; r < 2; ++r) {
      int c  = r * 256 + t;
      int rr = c >> 2, cc = (c & 3) * 8;
      *(uint4*)&As[rr * 32 + cc] = *(const uint4*)&A [(size_t)(row0 + rr) * K + k0 + cc];
      *(uint4*)&Bs[rr * 32 + cc] = *(const uint4*)&Bt[(size_t)(col0 + rr) * K + k0 + cc];
    }
    __syncthreads();

    bf16x8 af[4], bfv[4];
#pragma unroll
    for (int mi = 0; mi < 4; ++mi)
      af[mi] = *(bf16x8*)&As[(wm + mi * 16 + l16) * 32 + quad * 8];
#pragma unroll
    for (int ni = 0; ni < 4; ++ni)
      bfv[ni] = *(bf16x8*)&Bs[(wn + ni * 16 + l16) * 32 + quad * 8];
#pragma unroll
    for (int mi = 0; mi < 4; ++mi)
#pragma unroll
      for (int ni = 0; ni < 4; ++ni)
        acc[mi][ni] = __builtin_amdgcn_mfma_f32_16x16x32_bf16(af[mi], bfv[ni], acc[mi][ni], 0, 0, 0);
    __syncthreads();
  }

  // epilogue: C/D layout col = lane&15, row = quad*4 + reg
#pragma unroll
  for (int mi = 0; mi < 4; ++mi) {
#pragma unroll
    for (int ni = 0; ni < 4; ++ni) {
      int gc = col0 + wn + ni * 16 + l16;
      float bv = bias[gc];
#pragma unroll
      for (int r = 0; r < 4; ++r) {
        int gr = row0 + wm + mi * 16 + quad * 4 + r;
        float val = acc[mi][ni][r] + bv;
        if (OUT_BF16) ((unsigned short*)Cv)[(size_t)gr * Nt + gc] = f2bf(val);
        else          ((float*)Cv)[(size_t)gr * Nt + gc] = val;
      }
    }
  }
}

// ---------------- dilated local attention ----------------
// qkv: bf16 [ROWS, 1152], channel = s*384 + d*128 + h*32 + e
// out: bf16 [ROWS, 384],  channel = d*128 + h*32 + e
// One thread per (row i, dilation d, head h). 3 taps at offsets {-dil,0,+dil};
// softmax denominator gets +6 from the six structural zero taps (exp(0) each).
__global__ __launch_bounds__(256) void attn_kernel(const unsigned short* __restrict__ qkv,
                                                   unsigned short* __restrict__ out) {
  int tid = blockIdx.x * 256 + threadIdx.x;   // [0, ROWS*12)
  int i  = tid / 12;
  int dh = tid - i * 12;
  int d = dh >> 2, h = dh & 3;
  int dil = d + 1;
  int n = i & (SEQ - 1);
  size_t base = (size_t)i * QKV_CH + d * CD + h * HD;

  float q[32];
  {
    const uint4* qp = (const uint4*)(qkv + base);
#pragma unroll
    for (int c = 0; c < 4; ++c) unpack8(qp[c], &q[c * 8]);
  }

  float ex[3];
  int   valid[3];
#pragma unroll
  for (int kh = 0; kh < 3; ++kh) {
    int off = (kh - 1) * dil;
    int nn = n + off;
    int v = (nn >= 0) && (nn < SEQ);
    valid[kh] = v;
    float l = 0.f;
    if (v) {
      const uint4* kp = (const uint4*)(qkv + base + DIM + (ptrdiff_t)off * QKV_CH);
#pragma unroll
      for (int c = 0; c < 4; ++c) {
        float kk[8]; unpack8(kp[c], kk);
#pragma unroll
        for (int j = 0; j < 8; ++j) l += q[c * 8 + j] * kk[j];
      }
    }
    ex[kh] = __expf(l * SCALE);   // OOR -> l=0 -> exp=1 (matches zero-padded key)
  }
  float inv = 1.f / (ex[0] + ex[1] + ex[2] + 6.f);

  float o[32];
#pragma unroll
  for (int e = 0; e < 32; ++e) o[e] = 0.f;
#pragma unroll
  for (int kh = 0; kh < 3; ++kh) {
    if (!valid[kh]) continue;
    int off = (kh - 1) * dil;
    const uint4* vp = (const uint4*)(qkv + base + 2 * DIM + (ptrdiff_t)off * QKV_CH);
    float w = ex[kh];
#pragma unroll
    for (int c = 0; c < 4; ++c) {
      float vv[8]; unpack8(vp[c], vv);
#pragma unroll
      for (int j = 0; j < 8; ++j) o[c * 8 + j] += w * vv[j];
    }
  }

  unsigned short* op = out + (size_t)i * DIM + d * CD + h * HD;
#pragma unroll
  for (int c = 0; c < 4; ++c) {
    unsigned int w0 = (unsigned int)f2bf(o[c*8+0] * inv) | ((unsigned int)f2bf(o[c*8+1] * inv) << 16);
    unsigned int w1 = (unsigned int)f2bf(o[c*8+2] * inv) | ((unsigned int)f2bf(o[c*8+3] * inv) << 16);
    unsigned int w2 = (unsigned int)f2bf(o[c*8+4] * inv) | ((unsigned int)f2bf(o[c*8+5] * inv) << 16);
    unsigned int w3 = (unsigned int)f2bf(o[c*8+6] * inv) | ((unsigned int)f2bf(o[c*8+7] * inv) << 16);
    uint4 u; u.x = w0; u.y = w1; u.z = w2; u.w = w3;
    ((uint4*)op)[c] = u;
  }
}

// ---------------- launch ----------------
extern "C" void kernel_launch(void* const* d_in, const int* in_sizes, int n_in,
                              void* d_out, int out_size, void* d_ws, size_t ws_size,
                              hipStream_t stream) {
  const float* x     = (const float*)d_in[0];
  const float* Wqkv  = (const float*)d_in[1];
  const float* bqkv  = (const float*)d_in[2];
  const float* Wproj = (const float*)d_in[3];
  const float* bproj = (const float*)d_in[4];
  float* out = (float*)d_out;

  char* ws = (char*)d_ws;
  // byte offsets (256-aligned); total ~121 MB
  unsigned short* qkv_bf   = (unsigned short*)(ws);                 // 75,497,472 B
  unsigned short* x_bf     = (unsigned short*)(ws + 75497472);      // 25,165,824 B
  unsigned short* attn_bf  = (unsigned short*)(ws + 100663296);     // 25,165,824 B
  unsigned short* wqkv_bf  = (unsigned short*)(ws + 125829120);     //    884,736 B
  unsigned short* wproj_bf = (unsigned short*)(ws + 126713856);     //    294,912 B

  // converts
  cvt_f32_bf16<<<(ROWS * DIM / 4) / 256, 256, 0, stream>>>(x, x_bf, ROWS * DIM / 4);
  cvt_f32_bf16<<<(QKV_CH * DIM / 4 + 255) / 256, 256, 0, stream>>>(Wqkv, wqkv_bf, QKV_CH * DIM / 4);
  cvt_f32_bf16<<<(DIM * DIM / 4 + 255) / 256, 256, 0, stream>>>(Wproj, wproj_bf, DIM * DIM / 4);

  // qkv = x @ Wqkv^T + bqkv   (bf16 out)
  gemm_bt<1><<<dim3(ROWS / 128, QKV_CH / 128), 256, 0, stream>>>(
      x_bf, wqkv_bf, bqkv, (void*)qkv_bf, ROWS, QKV_CH, DIM);

  // dilated attention
  attn_kernel<<<(ROWS * 12) / 256, 256, 0, stream>>>(qkv_bf, attn_bf);

  // out = attn @ Wproj^T + bproj  (fp32 out)
  gemm_bt<0><<<dim3(ROWS / 128, DIM / 128), 256, 0, stream>>>(
      attn_bf, wproj_bf, bproj, (void*)out, ROWS, DIM, DIM);
}